// Round 1
// baseline (309.009 us; speedup 1.0000x reference)
//
#include <hip/hip_runtime.h>
#include <cstdint>
#include <cmath>

// ---------------- problem constants ----------------
#define BS    2
#define CC    64
#define FLAT  16384
#define NN    2048
#define KK    256
#define EPSBN 1e-5f
#define TINYF 1.17549435e-38f
// -ln(10000)/64 as f32
#define PE_SCALE -0.14391156831212787f

// JAX >= 0.4.30 defaults jax_threefry_partitionable=True. If absmax ~O(1),
// flip this to 0 (legacy split/random_bits path).
#define JAX_PARTITIONABLE 1

// ---------------- workspace layout (float offsets) ----------------
#define OFF_XI    0                          // [BS][NN][CC]   262144
#define OFF_XI1   (OFF_XI   + BS*NN*CC)      // [BS][NN][32]   131072
#define OFF_PROB  (OFF_XI1  + BS*NN*32)      // [BS][NN]       4096
#define OFF_LOGP  (OFF_PROB + BS*NN)         // [BS][NN]       4096
#define OFF_NEK   (OFF_LOGP + BS*NN)         // [BS][KK]       512
#define OFF_TF    (OFF_NEK  + BS*KK)         // [BS][KK][CC]   32768
#define OFF_M1    (OFF_TF   + BS*KK*CC)      // [BS][KK][32]   16384
#define OFF_DELTA (OFF_M1   + BS*KK*32)      // [BS][NN][CC]   262144
#define OFF_WF    (OFF_DELTA+ BS*NN*CC)      // [256][64]      16384
#define OFF_BF    (OFF_WF   + 256*CC)        // [64]           64
// total = 729664 floats ~= 2.79 MB

// ---------------- threefry2x32 (20 rounds, JAX layout) ----------------
__device__ __forceinline__ uint32_t rotl32(uint32_t x, int r) {
  return (x << r) | (x >> (32 - r));
}
__device__ __forceinline__ void tf2x32(uint32_t k0, uint32_t k1,
                                       uint32_t& x0, uint32_t& x1) {
  uint32_t k2 = k0 ^ k1 ^ 0x1BD11BDAu;
  x0 += k0; x1 += k1;
#define TFR(r) { x0 += x1; x1 = rotl32(x1, r); x1 ^= x0; }
  TFR(13) TFR(15) TFR(26) TFR(6)  x0 += k1; x1 += k2 + 1u;
  TFR(17) TFR(29) TFR(16) TFR(24) x0 += k2; x1 += k0 + 2u;
  TFR(13) TFR(15) TFR(26) TFR(6)  x0 += k0; x1 += k1 + 3u;
  TFR(17) TFR(29) TFR(16) TFR(24) x0 += k1; x1 += k2 + 4u;
  TFR(13) TFR(15) TFR(26) TFR(6)  x0 += k2; x1 += k0 + 5u;
#undef TFR
}
__device__ __forceinline__ void jax_key(int b, uint32_t& k0, uint32_t& k1) {
#if JAX_PARTITIONABLE
  uint32_t x0 = 0u, x1 = (uint32_t)b;
  tf2x32(0u, 42u, x0, x1);
  k0 = x0; k1 = x1;
#else
  uint32_t a0 = 0u, a1 = 2u, c0 = 1u, c1 = 3u;
  tf2x32(0u, 42u, a0, a1);
  tf2x32(0u, 42u, c0, c1);
  if (b == 0) { k0 = a0; k1 = c0; } else { k0 = a1; k1 = c1; }
#endif
}
__device__ __forceinline__ uint32_t jax_bits(uint32_t k0, uint32_t k1, uint32_t i) {
#if JAX_PARTITIONABLE
  uint32_t x0 = 0u, x1 = i;
  tf2x32(k0, k1, x0, x1);
  return x0 ^ x1;
#else
  const uint32_t half = (uint32_t)(KK * NN) / 2u;
  uint32_t x0, x1;
  if (i < half) { x0 = i; x1 = i + half; tf2x32(k0, k1, x0, x1); return x0; }
  else          { x0 = i - half; x1 = i; tf2x32(k0, k1, x0, x1); return x1; }
#endif
}

// ---------------- K0: fold resize weights: wf = w_r1@w_r2, bf = b_r1@w_r2+b_r2
__global__ void k0_fold(const float* __restrict__ w_r1, const float* __restrict__ b_r1,
                        const float* __restrict__ w_r2, const float* __restrict__ b_r2,
                        float* __restrict__ ws) {
  int c = blockIdx.x;      // 0..255
  int co = threadIdx.x;    // 0..63
  float acc = 0.f;
  for (int f = 0; f < 128; ++f)
    acc += w_r1[c * 128 + f] * w_r2[f * 64 + co];
  ws[OFF_WF + c * 64 + co] = acc;
  if (blockIdx.x == 0) {
    float bb = b_r2[co];
    for (int f = 0; f < 128; ++f) bb += b_r1[f] * w_r2[f * 64 + co];
    ws[OFF_BF + co] = bb;
  }
}

// ---------------- K1: gather xi = x[:,idx].T + pe, prob/logp, xi1 = (xi@W_p1)*a1
__global__ __launch_bounds__(256) void k1_xi(
    const float* __restrict__ input, const int* __restrict__ midx,
    const float* __restrict__ w_ne1, const float* __restrict__ b_ne1,
    const float* __restrict__ g_ne,  const float* __restrict__ be_ne,
    const float* __restrict__ w_ne2, const float* __restrict__ b_ne2,
    const float* __restrict__ w_p1,  const float* __restrict__ g_p1,
    float* __restrict__ ws) {
  int g = blockIdx.x * 256 + threadIdx.x;
  int b = g >> 11, n = g & (NN - 1);
  int pos = midx[b * NN + n];
  float fp = (float)pos;
  float xi[CC];
#pragma unroll
  for (int j = 0; j < 32; ++j) {
    float d = expf((float)(2 * j) * PE_SCALE);
    float ang = fp * d;
    xi[2 * j]     = sinf(ang);
    xi[2 * j + 1] = cosf(ang);
  }
#pragma unroll
  for (int c = 0; c < CC; ++c)
    xi[c] += input[(size_t)(b * CC + c) * FLAT + pos];
  {
    float* xw = ws + OFF_XI + (size_t)(b * NN + n) * CC;
#pragma unroll
    for (int c = 0; c < CC; ++c) xw[c] = xi[c];
  }
  // non-empty head: prob = sigmoid(relu(bn(xi@W+b)) @ w2 + b2)
  float p = 0.f;
#pragma unroll 1
  for (int j = 0; j < 32; ++j) {
    float z = b_ne1[j];
#pragma unroll
    for (int c = 0; c < CC; ++c) z += xi[c] * w_ne1[c * 32 + j];
    float a = g_ne[j] / sqrtf(1.f + EPSBN);
    float h = fmaxf(0.f, z * a + be_ne[j]);
    p += h * w_ne2[j];
  }
  p += b_ne2[0];
  float prob = 1.f / (1.f + expf(-p));
  ws[OFF_PROB + b * NN + n] = prob;
  ws[OFF_LOGP + b * NN + n] = logf(prob);
  // xi1 = (xi @ W_p1) * a1   (bias lives in m1)
  float* x1w = ws + OFF_XI1 + (size_t)(b * NN + n) * 32;
#pragma unroll 1
  for (int j = 0; j < 32; ++j) {
    float z = 0.f;
#pragma unroll
    for (int c = 0; c < CC; ++c) z += xi[c] * w_p1[c * 32 + j];
    float a = g_p1[j] / sqrtf(1.f + EPSBN);
    x1w[j] = z * a;
  }
}

// ---------------- K2: categorical draw k for sample b; emit tf, ne_k, m1
__global__ __launch_bounds__(256) void k2_sample(
    const int* __restrict__ midx,
    const float* __restrict__ w_p1, const float* __restrict__ b_p1,
    const float* __restrict__ g_p1, const float* __restrict__ be_p1,
    float* __restrict__ ws) {
  int b = blockIdx.x >> 8, k = blockIdx.x & 255;
  int tid = threadIdx.x;
  uint32_t kb0, kb1;
  jax_key(b, kb0, kb1);
  const float* logp = ws + OFF_LOGP + b * NN;
  const float NEGINF = -__builtin_inff();
  float bv = NEGINF; int bn = NN;
#pragma unroll 1
  for (int r = 0; r < 8; ++r) {
    int n = r * 256 + tid;
    uint32_t bits = jax_bits(kb0, kb1, (uint32_t)(k * NN + n));
    float f = __uint_as_float(0x3f800000u | (bits >> 9)) - 1.0f;
    float u = fmaxf(TINYF, f + TINYF);
    float gmb = -logf(-logf(u));
    float v = logp[n] + gmb;
    if (v > bv || (v == bv && n < bn)) { bv = v; bn = n; }
  }
  __shared__ float sv[256];
  __shared__ int   sn[256];
  __shared__ float mpe[CC];
  sv[tid] = bv; sn[tid] = bn;
  __syncthreads();
  for (int s = 128; s > 0; s >>= 1) {
    if (tid < s) {
      float v2 = sv[tid + s]; int n2 = sn[tid + s];
      if (v2 > sv[tid] || (v2 == sv[tid] && n2 < sn[tid])) { sv[tid] = v2; sn[tid] = n2; }
    }
    __syncthreads();
  }
  int best = sn[0];
  if (tid == 0)
    ws[OFF_NEK + b * KK + k] = ws[OFF_PROB + b * NN + best];
  if (tid < CC) {
    int c = tid;
    ws[OFF_TF + (size_t)(b * KK + k) * CC + c] =
        ws[OFF_XI + (size_t)(b * NN + best) * CC + c];
    int pos = midx[b * NN + best];
    int j = c >> 1;
    float ang = (float)pos * expf((float)(2 * j) * PE_SCALE);
    mpe[c] = (c & 1) ? cosf(ang) : sinf(ang);
  }
  __syncthreads();
  if (tid < 32) {
    int j = tid;
    float acc = b_p1[j];
#pragma unroll
    for (int c = 0; c < CC; ++c) acc += mpe[c] * w_p1[c * 32 + j];
    float a = g_p1[j] / sqrtf(1.f + EPSBN);
    ws[OFF_M1 + (size_t)(b * KK + k) * 32 + j] = acc * a + be_p1[j];
  }
}

// ---------------- K3: heavy N x K pairwise MLP + weighted-average + delta
__global__ __launch_bounds__(256) void k3_pair(
    const float* __restrict__ w_p2, const float* __restrict__ b_p2,
    const float* __restrict__ g_p2, const float* __restrict__ be_p2,
    const float* __restrict__ w_p3, const float* __restrict__ b_p3,
    float* __restrict__ ws) {
  __shared__ __align__(16) float m1s[KK * 33];   // padded rows: conflict-free
  __shared__ __align__(16) float w2s[1024];
  __shared__ float c2f[32], w3l[32], xi1l[32];
  __shared__ float Pil[KK], Pel[KK];
  __shared__ float pI[4 * 64], pE[4 * 64], pS[4], pSE[4];
  __shared__ float xIl[CC], xEl[CC];
  int tid = threadIdx.x;
  int b = blockIdx.x >> 9;            // 512 blocks per sample
  int n0 = (blockIdx.x & 511) * 4;
  for (int e = tid; e < KK * 32; e += 256) {
    int k = e >> 5, j = e & 31;
    m1s[k * 33 + j] = ws[OFF_M1 + (size_t)b * KK * 32 + e];
  }
  for (int e = tid; e < 1024; e += 256) {
    int j = e & 31;
    w2s[e] = w_p2[e] * (g_p2[j] / sqrtf(1.f + EPSBN));
  }
  if (tid < 32) {
    c2f[tid] = b_p2[tid] * (g_p2[tid] / sqrtf(1.f + EPSBN)) + be_p2[tid];
    w3l[tid] = w_p3[tid];
  }
  float nekv = ws[OFF_NEK + b * KK + tid];
  float b3 = b_p3[0];
  const float* tfg = ws + OFF_TF + (size_t)b * KK * CC;
  const float* wfg = ws + OFF_WF;
  __syncthreads();
#pragma unroll 1
  for (int nn = 0; nn < 4; ++nn) {
    int n = n0 + nn;
    if (tid < 32) xi1l[tid] = ws[OFF_XI1 + (size_t)(b * NN + n) * 32 + tid];
    __syncthreads();
    // thread == one k
    float hp1[32];
#pragma unroll
    for (int j = 0; j < 32; ++j)
      hp1[j] = fmaxf(0.f, xi1l[j] + m1s[tid * 33 + j]);
    float z[32];
#pragma unroll
    for (int j = 0; j < 32; ++j) z[j] = c2f[j];
#pragma unroll
    for (int jj = 0; jj < 32; ++jj) {
      float a = hp1[jj];
      const float4* row = (const float4*)&w2s[jj * 32];
#pragma unroll
      for (int q4 = 0; q4 < 8; ++q4) {
        float4 w = row[q4];
        z[q4 * 4 + 0] += a * w.x; z[q4 * 4 + 1] += a * w.y;
        z[q4 * 4 + 2] += a * w.z; z[q4 * 4 + 3] += a * w.w;
      }
    }
    float zp = b3;
#pragma unroll
    for (int j = 0; j < 32; ++j) zp += fmaxf(0.f, z[j]) * w3l[j];
    float P = 1.f / (1.f + expf(-zp));
    Pil[tid] = P * nekv;
    Pel[tid] = (1.f - P) * nekv;
    __syncthreads();
    // reduction over k: x_intra/x_inter
    int c = tid & 63, q = tid >> 6;
    float aI = 0.f, aE = 0.f, aS = 0.f, aSE = 0.f;
#pragma unroll 4
    for (int t = 0; t < 64; ++t) {
      int k2 = q * 64 + t;
      float pi = Pil[k2], pe_ = Pel[k2];
      float tv = tfg[(size_t)k2 * CC + c];
      aI += pi * tv; aE += pe_ * tv; aS += pi; aSE += pe_;
    }
    pI[q * 64 + c] = aI; pE[q * 64 + c] = aE;
    if (c == 0) { pS[q] = aS; pSE[q] = aSE; }
    __syncthreads();
    if (tid < CC) {
      float si = pS[0] + pS[1] + pS[2] + pS[3];
      float se = pSE[0] + pSE[1] + pSE[2] + pSE[3];
      xIl[tid] = (pI[tid] + pI[64 + tid] + pI[128 + tid] + pI[192 + tid]) / si;
      xEl[tid] = (pE[tid] + pE[64 + tid] + pE[128 + tid] + pE[192 + tid]) / se;
    }
    __syncthreads();
    if (tid < CC) {
      int co = tid; float d = 0.f;
#pragma unroll 4
      for (int c2 = 0; c2 < CC; ++c2) {
        d += xIl[c2] * wfg[(64 + c2) * CC + co];
        d += xEl[c2] * wfg[(128 + c2) * CC + co];
      }
      ws[OFF_DELTA + (size_t)(b * NN + n) * CC + co] = d;
    }
    __syncthreads();
  }
}

// ---------------- K4: base resize  y = in @ (wf[0:64]+wf[192:256]) + bf
__global__ __launch_bounds__(256) void k4_base(
    const float* __restrict__ input, float* __restrict__ out,
    const float* __restrict__ ws) {
  __shared__ __align__(16) float wfa[64 * 64];
  __shared__ float bfl[64];
  int tid = threadIdx.x;
  const float* wf = ws + OFF_WF;
  for (int e = tid; e < 4096; e += 256) {
    int c = e >> 6, co = e & 63;
    wfa[e] = wf[c * 64 + co] + wf[(192 + c) * 64 + co];
  }
  if (tid < 64) bfl[tid] = ws[OFF_BF + tid];
  __syncthreads();
  int v = blockIdx.x * 256 + tid;
  int b = v >> 14, pos = v & (FLAT - 1);
  float acc[64];
#pragma unroll
  for (int co = 0; co < 64; ++co) acc[co] = bfl[co];
#pragma unroll 1
  for (int c = 0; c < 64; ++c) {
    float xv = input[(size_t)(b * CC + c) * FLAT + pos];
    const float4* row = (const float4*)&wfa[c * 64];
#pragma unroll
    for (int q4 = 0; q4 < 16; ++q4) {
      float4 w = row[q4];
      acc[q4 * 4 + 0] += xv * w.x; acc[q4 * 4 + 1] += xv * w.y;
      acc[q4 * 4 + 2] += xv * w.z; acc[q4 * 4 + 3] += xv * w.w;
    }
  }
#pragma unroll
  for (int co = 0; co < 64; ++co)
    out[(size_t)(b * CC + co) * FLAT + pos] = acc[co];
}

// ---------------- K5: scatter-add the ctx contribution at masked voxels
__global__ __launch_bounds__(256) void k5_scatter(
    const int* __restrict__ midx, float* __restrict__ out,
    const float* __restrict__ ws) {
  int g = blockIdx.x * 256 + threadIdx.x;
  int b = g >> 17;                 // NN*CC = 131072 = 2^17
  int r = g & (NN * CC - 1);
  int co = r >> 11, n = r & (NN - 1);
  int pos = midx[b * NN + n];
  size_t oi = (size_t)(b * CC + co) * FLAT + pos;
  out[oi] += ws[OFF_DELTA + (size_t)(b * NN + n) * CC + co];
}

// ---------------- launch ----------------
extern "C" void kernel_launch(void* const* d_in, const int* in_sizes, int n_in,
                              void* d_out, int out_size, void* d_ws, size_t ws_size,
                              hipStream_t stream) {
  const float* input = (const float*)d_in[0];
  const int*   midx  = (const int*)  d_in[1];
  const float* w_ne1 = (const float*)d_in[2];
  const float* b_ne1 = (const float*)d_in[3];
  const float* g_ne  = (const float*)d_in[4];
  const float* be_ne = (const float*)d_in[5];
  const float* w_ne2 = (const float*)d_in[6];
  const float* b_ne2 = (const float*)d_in[7];
  const float* w_p1  = (const float*)d_in[8];
  const float* b_p1  = (const float*)d_in[9];
  const float* g_p1  = (const float*)d_in[10];
  const float* be_p1 = (const float*)d_in[11];
  const float* w_p2  = (const float*)d_in[12];
  const float* b_p2  = (const float*)d_in[13];
  const float* g_p2  = (const float*)d_in[14];
  const float* be_p2 = (const float*)d_in[15];
  const float* w_p3  = (const float*)d_in[16];
  const float* b_p3  = (const float*)d_in[17];
  const float* w_r1  = (const float*)d_in[18];
  const float* b_r1  = (const float*)d_in[19];
  const float* w_r2  = (const float*)d_in[20];
  const float* b_r2  = (const float*)d_in[21];
  float* out = (float*)d_out;
  float* ws  = (float*)d_ws;

  k0_fold<<<dim3(256), dim3(64), 0, stream>>>(w_r1, b_r1, w_r2, b_r2, ws);
  k1_xi<<<dim3(BS * NN / 256), dim3(256), 0, stream>>>(
      input, midx, w_ne1, b_ne1, g_ne, be_ne, w_ne2, b_ne2, w_p1, g_p1, ws);
  k2_sample<<<dim3(BS * KK), dim3(256), 0, stream>>>(
      midx, w_p1, b_p1, g_p1, be_p1, ws);
  k3_pair<<<dim3(BS * NN / 4), dim3(256), 0, stream>>>(
      w_p2, b_p2, g_p2, be_p2, w_p3, b_p3, ws);
  k4_base<<<dim3(BS * FLAT / 256), dim3(256), 0, stream>>>(input, out, ws);
  k5_scatter<<<dim3(BS * NN * CC / 256), dim3(256), 0, stream>>>(midx, out, ws);
}